// Round 1
// baseline (1005.743 us; speedup 1.0000x reference)
//
#include <hip/hip_runtime.h>

// TemporalLayer: T=64, N=2048, D=512, weight=0.5, causal attention, no sqrt(d) scale.
// fp16 MFMA (v_mfma_f32_16x16x32_f16, fp32 accum) internally; fp32 in/out.
//
// R1 changes vs 1565us baseline (theory: barrier/latency-bound, 7.5% MFMA util):
//  1. Weights pre-shuffled to MFMA-FRAGMENT-MAJOR layout in ws; B/A weight
//     fragments are read DIRECTLY from global (L2-resident, 1KB contiguous per
//     wave-fragment). Removes per-kb 32KB/block weight global->reg->LDS stage,
//     its LDS traffic, and the WAR hazard that forced a 2nd barrier per kb.
//  2. t-tile (x+pos -> fp16) double-buffered in LDS: ONE barrier per kb.
//  3. Hot-loop barriers are raw: s_waitcnt lgkmcnt(0); s_barrier; sched_barrier(0).
//     vmcnt NOT drained -> next-tile x/pos loads + weight-fragment loads stay in
//     flight across the barrier; waits land at first use after the MFMAs.
// fp16 out-scratch still lives in the UPPER HALF of each node's fp32 out slot.

#define TT 64
#define NN 2048
#define DD 512

typedef _Float16 f16x8 __attribute__((ext_vector_type(8)));
typedef float    f32x4 __attribute__((ext_vector_type(4)));

#define MFMA16(a,b,c) __builtin_amdgcn_mfma_f32_16x16x32_f16((a),(b),(c),0,0,0)

#define RAW_BARRIER() do { \
    asm volatile("s_waitcnt lgkmcnt(0)" ::: "memory"); \
    __builtin_amdgcn_s_barrier(); \
    __builtin_amdgcn_sched_barrier(0); \
  } while (0)

// ---- weights -> fp16 fragment-major ----
// Fragment layout for 16x16x32 f16 MFMA, operand rows e (out col), k = d:
//   tile(e,d) = (e>>4)*16 + (d>>5)   (32 e-blocks x 16 d-blocks, 512 tiles/mat)
//   lane(e,d) = ((d>>3)&3)*16 + (e&15), half j = d&7
//   half offset = tile*512 + lane*8 + j  -> each wave fragment = contiguous 1KB.
// mats: 0=Wq^T 1=Wk^T 2=Wv^T (src [d][e], transposed) 3=lin_w (src [e][d]).
__global__ __launch_bounds__(256) void prep_weights(
    const float* __restrict__ Wq, const float* __restrict__ Wk,
    const float* __restrict__ Wv, const float* __restrict__ lw,
    _Float16* __restrict__ out)
{
  int gid = blockIdx.x * 256 + threadIdx.x;   // 131072 threads, 8 halfs each
  int mat = gid >> 15;
  int r   = gid & 32767;
  int tile = r >> 6;          // 0..511
  int l    = r & 63;          // lane slot
  int rowblk = tile >> 4;     // e block
  int kbb    = tile & 15;     // d block
  int e  = rowblk * 16 + (l & 15);
  int d0 = kbb * 32 + (l >> 4) * 8;
  union { _Float16 h[8]; uint4 u; } o;
  if (mat < 3) {
    const float* W = (mat == 0) ? Wq : (mat == 1) ? Wk : Wv;
    #pragma unroll
    for (int j = 0; j < 8; ++j)
      o.h[j] = (_Float16)W[(size_t)(d0 + j) * DD + e];   // transpose
  } else {
    #pragma unroll
    for (int j = 0; j < 8; ++j)
      o.h[j] = (_Float16)lw[(size_t)e * DD + d0 + j];
  }
  *(uint4*)(out + (size_t)gid * 8) = o.u;
}

// ---- fused per-node: temporal -> q,k -> scores -> softmax -> v -> out=attn@v ----
// grid = 2048 nodes, block = 512 (8 waves). LDS 54272 B.
// MFMA 16x16x32 f16: A[m=l&15][k=quad*8+j]; B[n=l&15][k=quad*8+j];
// C/D: col=l&15, row=quad*4+reg.
__global__ __launch_bounds__(512) void attn_fused(
    const float* __restrict__ x, const float* __restrict__ pos,
    const _Float16* __restrict__ WF, _Float16* __restrict__ outp)
{
  __shared__ char smem[54272];
  char* const tst0 = smem;           // [64][40] f16 stride 80 (t tile, buf 0)
  char* const tst1 = smem + 5120;    // buf 1
  char* const qdp  = smem + 10240;   // [64][136] f16 stride 272 (q dump) -- aliased:
  char* const scb  = smem + 10240;   //   [64][68] f32 stride 272 (scores)
  char* const vdp  = smem + 10240;   //   8 x [32][68] f16 stride 136 (vT dump, 34816 B)
  char* const kdp  = smem + 27648;   // [64][136] f16 stride 272 (k dump)
  char* const atn  = smem + 45056;   // [64][72] f16 stride 144 (attn probs)

  const int n    = blockIdx.x;
  const int tid  = threadIdx.x;
  const int wid  = tid >> 6;
  const int lane = tid & 63;
  const int quad = lane >> 4;
  const int l15  = lane & 15;
  const size_t scrbase = (size_t)n * 65536 + 32768;   // fp16 scratch (halfs)

  const _Float16* const Fq = WF;
  const _Float16* const Fk = WF + 262144;
  const _Float16* const Fv = WF + 524288;

  const int srow = tid >> 3, si = tid & 7;   // staging decomposition
  auto t_issue = [&](int kb, f32x4& xv, f32x4& pv) {
    xv = *(const f32x4*)(x + ((size_t)srow * NN + n) * DD + kb * 32 + 4 * si);
    pv = *(const f32x4*)(pos + (size_t)srow * DD + kb * 32 + 4 * si);
  };
  auto t_store = [&](char* buf, const f32x4& xv, const f32x4& pv) {
    union { _Float16 h[4]; unsigned long long u; } o;
    #pragma unroll
    for (int j = 0; j < 4; ++j) o.h[j] = (_Float16)(xv[j] + pv[j]);
    *(unsigned long long*)(buf + srow * 80 + 8 * si) = o.u;
  };

  f32x4 sacc[2] = {};   // this wave's 2 score tiles, accumulated over all 512 e

  for (int ph = 0; ph < 2; ++ph) {          // e in [ph*256, ph*256+256)
    f32x4 acc[4][4] = {};                   // q- or k-slice [64 t][64 e] of this wave
    const bool isK = (wid >= 4);
    const int  esl = wid & 3;
    // wave's e-base = ph*256 + esl*64 -> rowblk base = ph*16 + esl*4
    const _Float16* const fwave =
        (isK ? Fk : Fq) + (size_t)(ph * 16 + esl * 4) * 8192 + (size_t)lane * 8;

    {
      f32x4 xa, pa;
      t_issue(0, xa, pa);
      t_store(tst0, xa, pa);
    }
    char* tcur = tst0; char* tnxt = tst1;
    for (int kb = 0; kb < 16; ++kb) {       // K blocks of 32
      f16x8 bf[4];                          // weight fragments straight from L2
      #pragma unroll
      for (int ct = 0; ct < 4; ++ct)
        bf[ct] = *(const f16x8*)(fwave + (size_t)kb * 512 + (size_t)ct * 8192);
      f32x4 xb, pb;
      if (kb < 15) t_issue(kb + 1, xb, pb);
      RAW_BARRIER();                        // tst writes visible; vmcnt stays in flight
      f16x8 af[4];
      #pragma unroll
      for (int rt = 0; rt < 4; ++rt)
        af[rt] = *(const f16x8*)(tcur + (16 * rt + l15) * 80 + quad * 16);
      #pragma unroll
      for (int ct = 0; ct < 4; ++ct)
        #pragma unroll
        for (int rt = 0; rt < 4; ++rt)
          acc[rt][ct] = MFMA16(af[rt], bf[ct], acc[rt][ct]);
      if (kb < 15) t_store(tnxt, xb, pb);
      char* t = tcur; tcur = tnxt; tnxt = t;
    }

    // dump 128-col blocks of q,k -> LDS, accumulate scores += q_c @ k_c^T
    for (int r = 0; r < 2; ++r) {
      __syncthreads();
      if ((esl >> 1) == r) {
        char* dst = isK ? kdp : qdp;
        const int colbase = (esl & 1) * 64;
        #pragma unroll
        for (int rt = 0; rt < 4; ++rt)
          #pragma unroll
          for (int ct = 0; ct < 4; ++ct)
            #pragma unroll
            for (int rg = 0; rg < 4; ++rg)
              *(_Float16*)(dst + (16*rt + quad*4 + rg)*272 + (colbase + 16*ct + l15)*2)
                  = (_Float16)acc[rt][ct][rg];
      }
      __syncthreads();
      const int srt = wid >> 1, sct0 = (wid & 1) * 2;
      #pragma unroll
      for (int ks = 0; ks < 4; ++ks) {
        f16x8 aq = *(const f16x8*)(qdp + (16*srt + l15)*272 + ks*64 + quad*16);
        #pragma unroll
        for (int j = 0; j < 2; ++j) {
          f16x8 bk = *(const f16x8*)(kdp + (16*(sct0+j) + l15)*272 + ks*64 + quad*16);
          sacc[j] = MFMA16(aq, bk, sacc[j]);
        }
      }
    }
  }

  // scores -> LDS (f32), causal softmax, attn probs (fp16) -> atn
  __syncthreads();
  {
    const int srt = wid >> 1, sct0 = (wid & 1) * 2;
    #pragma unroll
    for (int j = 0; j < 2; ++j)
      #pragma unroll
      for (int rg = 0; rg < 4; ++rg)
        *(float*)(scb + (16*srt + quad*4 + rg)*272 + (16*(sct0+j) + l15)*4) = sacc[j][rg];
  }
  __syncthreads();
  {
    const int row = tid >> 3, i = tid & 7;   // 8 threads per row, 8 cols each
    f32x4 s0 = *(const f32x4*)(scb + row*272 + 32*i);
    f32x4 s1 = *(const f32x4*)(scb + row*272 + 32*i + 16);
    float s[8] = { s0[0],s0[1],s0[2],s0[3], s1[0],s1[1],s1[2],s1[3] };
    float m = -3.0e38f;
    #pragma unroll
    for (int j = 0; j < 8; ++j) if (8*i + j <= row) m = fmaxf(m, s[j]);
    m = fmaxf(m, __shfl_xor(m, 1));
    m = fmaxf(m, __shfl_xor(m, 2));
    m = fmaxf(m, __shfl_xor(m, 4));
    float e[8]; float sum = 0.f;
    #pragma unroll
    for (int j = 0; j < 8; ++j) {
      e[j] = (8*i + j <= row) ? __expf(s[j] - m) : 0.f;   // NEG_BIG mask == exact zero
      sum += e[j];
    }
    sum += __shfl_xor(sum, 1);
    sum += __shfl_xor(sum, 2);
    sum += __shfl_xor(sum, 4);
    const float inv = 1.0f / sum;
    union { _Float16 h[8]; uint4 u; } o;
    #pragma unroll
    for (int j = 0; j < 8; ++j) o.h[j] = (_Float16)(e[j] * inv);
    *(uint4*)(atn + row*144 + 16*i) = o.u;
  }

  // V projection: wave w owns v[:, 64w..64w+63]; weights direct from L2, t dbuf'd.
  f32x4 vacc[4][4] = {};
  {
    const _Float16* const fwv = Fv + (size_t)(wid * 4) * 8192 + (size_t)lane * 8;
    {
      f32x4 xa, pa;
      t_issue(0, xa, pa);
      t_store(tst0, xa, pa);    // tst long dead; stragglers only touch scb/atn
    }
    char* tcur = tst0; char* tnxt = tst1;
    for (int kb = 0; kb < 16; ++kb) {
      f16x8 bf[4];
      #pragma unroll
      for (int ct = 0; ct < 4; ++ct)
        bf[ct] = *(const f16x8*)(fwv + (size_t)kb * 512 + (size_t)ct * 8192);
      f32x4 xb, pb;
      if (kb < 15) t_issue(kb + 1, xb, pb);
      RAW_BARRIER();
      f16x8 af[4];
      #pragma unroll
      for (int rt = 0; rt < 4; ++rt)
        af[rt] = *(const f16x8*)(tcur + (16 * rt + l15) * 80 + quad * 16);
      #pragma unroll
      for (int ct = 0; ct < 4; ++ct)
        #pragma unroll
        for (int rt = 0; rt < 4; ++rt)
          vacc[rt][ct] = MFMA16(af[rt], bf[ct], vacc[rt][ct]);
      if (kb < 15) t_store(tnxt, xb, pb);
      char* t = tcur; tcur = tnxt; tnxt = t;
    }
  }

  // out = attn @ v, computed transposed (D[m=d][n=t]) so stores pack 4 consecutive d.
  __syncthreads();   // all waves past softmax/V loop before vdp overwrites qdp/kdp
  char* const vd = vdp + wid * 4352;   // wave-private vT dump [32][68] f16 stride 136
  #pragma unroll
  for (int h = 0; h < 2; ++h) {
    #pragma unroll
    for (int c = 0; c < 2; ++c) {
      const int ct = 2*h + c;
      #pragma unroll
      for (int rt = 0; rt < 4; ++rt)
        #pragma unroll
        for (int rg = 0; rg < 4; ++rg)
          *(_Float16*)(vd + (16*c + l15)*136 + (16*rt + quad*4 + rg)*2)
              = (_Float16)vacc[rt][ct][rg];
    }
    f32x4 oacc[2][4] = {};
    #pragma unroll
    for (int ks = 0; ks < 2; ++ks) {
      f16x8 av[2];
      #pragma unroll
      for (int mt = 0; mt < 2; ++mt)
        av[mt] = *(const f16x8*)(vd + (16*mt + l15)*136 + ks*64 + quad*16);
      #pragma unroll
      for (int nt = 0; nt < 4; ++nt) {
        f16x8 ba = *(const f16x8*)(atn + (16*nt + l15)*144 + ks*64 + quad*16);
        #pragma unroll
        for (int mt = 0; mt < 2; ++mt)
          oacc[mt][nt] = MFMA16(av[mt], ba, oacc[mt][nt]);
      }
    }
    #pragma unroll
    for (int mt = 0; mt < 2; ++mt)
      #pragma unroll
      for (int nt = 0; nt < 4; ++nt) {
        const int d0 = 64*wid + 32*h + 16*mt + quad*4;
        const int tq = 16*nt + l15;
        union { _Float16 h4[4]; uint2 u; } o;
        #pragma unroll
        for (int rg = 0; rg < 4; ++rg) o.h4[rg] = (_Float16)oacc[mt][nt][rg];
        *(uint2*)(outp + scrbase + (size_t)tq * DD + d0) = o.u;   // fp16 scratch
      }
  }
}

// ---- ff = relu(out @ lin_w^T + b); y = 0.5*(ff+out) + (x+pos), fp32 output ----
// A = lin_w fragments direct from L2 (fragment-major); out tile dbuf'd in LDS.
// In-place on d_out: pre-read scratch -> regs before fp32 writes.
__global__ __launch_bounds__(512) void ff_final(
    const _Float16* outp, const float* __restrict__ x,
    const float* __restrict__ pos, const _Float16* __restrict__ lwF,
    const float* __restrict__ lb, float* y)
{
  __shared__ char smem[10240];
  char* const ost0 = smem;          // [64][40] f16 stride 80 (out tile, buf 0)
  char* const ost1 = smem + 5120;   // buf 1

  const int n = blockIdx.x;
  const int tid = threadIdx.x;
  const int wid = tid >> 6, lane = tid & 63, quad = lane >> 4, l15 = lane & 15;
  const size_t scrbase = (size_t)n * 65536 + 32768;

  const _Float16* const fA = lwF + (size_t)(wid * 4) * 8192 + (size_t)lane * 8;

  const int srow = tid >> 3, si = tid & 7;
  auto o_issue = [&](int kb, unsigned long long& v) {
    v = *(const unsigned long long*)(outp + scrbase + (size_t)srow * DD + kb * 32 + 4 * si);
  };
  auto o_store = [&](char* buf, unsigned long long v) {
    *(unsigned long long*)(buf + srow * 80 + 8 * si) = v;
  };

  f32x4 acc[4][4] = {};            // ffT [64 e of this wave][64 t]
  {
    unsigned long long va;
    o_issue(0, va);
    o_store(ost0, va);
  }
  char* ocur = ost0; char* onxt = ost1;
  for (int kb = 0; kb < 16; ++kb) {
    f16x8 af[4];                   // lin_w fragments straight from L2
    #pragma unroll
    for (int mt = 0; mt < 4; ++mt)
      af[mt] = *(const f16x8*)(fA + (size_t)kb * 512 + (size_t)mt * 8192);
    unsigned long long vb = 0;
    if (kb < 15) o_issue(kb + 1, vb);
    RAW_BARRIER();
    #pragma unroll
    for (int nt = 0; nt < 4; ++nt) {
      f16x8 bo = *(const f16x8*)(ocur + (16 * nt + l15) * 80 + quad * 16);
      #pragma unroll
      for (int mt = 0; mt < 4; ++mt)
        acc[mt][nt] = MFMA16(af[mt], bo, acc[mt][nt]);
    }
    if (kb < 15) o_store(onxt, vb);
    char* t = ocur; ocur = onxt; onxt = t;
  }

  // Phase 1: pre-read ALL of this lane's scratch out-values into registers.
  uint2 ovv[4][4];
  #pragma unroll
  for (int mt = 0; mt < 4; ++mt) {
    const int e0 = wid*64 + 16*mt + quad*4;
    #pragma unroll
    for (int nt = 0; nt < 4; ++nt) {
      const int tq = 16*nt + l15;
      ovv[mt][nt] = *(const uint2*)(outp + scrbase + (size_t)tq * DD + e0);
    }
  }
  __syncthreads();   // drains vmcnt: every scratch read done before any fp32 write

  // Phase 2: epilogue + fp32 writes (these overwrite the node's scratch bytes).
  #pragma unroll
  for (int mt = 0; mt < 4; ++mt) {
    const int e0 = wid*64 + 16*mt + quad*4;
    f32x4 bias = *(const f32x4*)(lb + e0);
    #pragma unroll
    for (int nt = 0; nt < 4; ++nt) {
      const int tq = 16*nt + l15;
      const size_t base = ((size_t)n * TT + tq) * DD + e0;
      union { _Float16 h4[4]; uint2 u; } ov;
      ov.u = ovv[mt][nt];
      f32x4 xv = *(const f32x4*)(x + ((size_t)tq * NN + n) * DD + e0);
      f32x4 pv = *(const f32x4*)(pos + (size_t)tq * DD + e0);
      f32x4 ro;
      #pragma unroll
      for (int rg = 0; rg < 4; ++rg) {
        float ff = acc[mt][nt][rg] + bias[rg];
        ff = ff > 0.f ? ff : 0.f;
        ro[rg] = 0.5f * (ff + (float)ov.h4[rg]) + xv[rg] + pv[rg];  // exact fp32 temporal
      }
      *(f32x4*)(y + base) = ro;
    }
  }
}

extern "C" void kernel_launch(void* const* d_in, const int* in_sizes, int n_in,
                              void* d_out, int out_size, void* d_ws, size_t ws_size,
                              hipStream_t stream) {
  (void)in_sizes; (void)n_in; (void)out_size; (void)ws_size;
  const float* x   = (const float*)d_in[0];
  const float* pos = (const float*)d_in[1];
  const float* Wq  = (const float*)d_in[2];
  const float* Wk  = (const float*)d_in[3];
  const float* Wv  = (const float*)d_in[4];
  const float* lw  = (const float*)d_in[5];
  const float* lb  = (const float*)d_in[6];
  _Float16* wsW = (_Float16*)d_ws;   // 4 * 262144 fp16 = 2 MB, fragment-major

  prep_weights<<<512, 256, 0, stream>>>(Wq, Wk, Wv, lw, wsW);
  attn_fused<<<2048, 512, 0, stream>>>(x, pos, wsW, (_Float16*)d_out);
  ff_final<<<2048, 512, 0, stream>>>((const _Float16*)d_out, x, pos,
                                     wsW + 786432, lb, (float*)d_out);
}

// Round 5
// 953.543 us; speedup vs baseline: 1.0547x; 1.0547x over previous
//
#include <hip/hip_runtime.h>

// TemporalLayer: T=64, N=2048, D=512, weight=0.5, causal attention, no sqrt(d) scale.
// fp16 MFMA (v_mfma_f32_16x16x32_f16, fp32 accum) internally; fp32 in/out.
//
// R2 changes vs R1 (1005us; attn 430us: MfmaUtil 22%, HBM 16%, 419MB fetch):
//  1. attn_fused: temporal tile (x+pos -> fp16) staged ONCE into a persistent
//     XOR-swizzled LDS tile (64KB). Q/K/V projection loops have ZERO barriers
//     and no global x dependence -> x fetched 1x instead of 3x, and the
//     per-kb barrier<->HBM-latency coupling (the R1 bottleneck) is gone.
//     LDS 107KB -> 1 block/CU; loops fully unrolled so the compiler pipelines
//     L2 fragment loads + conflict-free ds_reads under the MFMAs.
//  2. ff_final: scratch out-tile staged once into 64KB swizzled LDS (2 blk/CU),
//     zero in-loop barriers; epilogue re-reads out-values from LDS (removes the
//     scattered global scratch re-read + vmcnt-drain barrier).
//  3. Swizzle byte ^= (row&7)<<4: b128 fragment reads land on 8 distinct 16B
//     slots covering all 32 banks -> minimum-cycle (conflict-free) access.
// fp16 out-scratch still lives in the UPPER HALF of each node's fp32 out slot.
// (R5 = R2 resubmitted verbatim. Failure history: R2 GPUAcquisitionTimeout
//  (broker at capacity), R3/R4 "container failed twice" — same signature R0's
//  known-good kernel hit once. Triple audit: no hang/fault path exists.)

#define TT 64
#define NN 2048
#define DD 512

typedef _Float16 f16x8 __attribute__((ext_vector_type(8)));
typedef float    f32x4 __attribute__((ext_vector_type(4)));

#define MFMA16(a,b,c) __builtin_amdgcn_mfma_f32_16x16x32_f16((a),(b),(c),0,0,0)

// ---- weights -> fp16 fragment-major ----
// Fragment layout for 16x16x32 f16 MFMA, operand rows e (out col), k = d:
//   tile(e,d) = (e>>4)*16 + (d>>5)   (32 e-blocks x 16 d-blocks, 512 tiles/mat)
//   lane(e,d) = ((d>>3)&3)*16 + (e&15), half j = d&7
//   half offset = tile*512 + lane*8 + j  -> each wave fragment = contiguous 1KB.
// mats: 0=Wq^T 1=Wk^T 2=Wv^T (src [d][e], transposed) 3=lin_w (src [e][d]).
__global__ __launch_bounds__(256) void prep_weights(
    const float* __restrict__ Wq, const float* __restrict__ Wk,
    const float* __restrict__ Wv, const float* __restrict__ lw,
    _Float16* __restrict__ out)
{
  int gid = blockIdx.x * 256 + threadIdx.x;   // 131072 threads, 8 halfs each
  int mat = gid >> 15;
  int r   = gid & 32767;
  int tile = r >> 6;          // 0..511
  int l    = r & 63;          // lane slot
  int rowblk = tile >> 4;     // e block
  int kbb    = tile & 15;     // d block
  int e  = rowblk * 16 + (l & 15);
  int d0 = kbb * 32 + (l >> 4) * 8;
  union { _Float16 h[8]; uint4 u; } o;
  if (mat < 3) {
    const float* W = (mat == 0) ? Wq : (mat == 1) ? Wk : Wv;
    #pragma unroll
    for (int j = 0; j < 8; ++j)
      o.h[j] = (_Float16)W[(size_t)(d0 + j) * DD + e];   // transpose
  } else {
    #pragma unroll
    for (int j = 0; j < 8; ++j)
      o.h[j] = (_Float16)lw[(size_t)e * DD + d0 + j];
  }
  *(uint4*)(out + (size_t)gid * 8) = o.u;
}

// ---- fused per-node: temporal -> q,k -> scores -> softmax -> v -> out=attn@v ----
// grid = 2048 nodes, block = 512 (8 waves). LDS 109568 B (1 block/CU).
// MFMA 16x16x32 f16: A[m=l&15][k=quad*8+j]; B[n=l&15][k=quad*8+j];
// C/D: col=l&15, row=quad*4+reg.
__global__ __launch_bounds__(512) void attn_fused(
    const float* __restrict__ x, const float* __restrict__ pos,
    const _Float16* __restrict__ WF, _Float16* __restrict__ outp)
{
  __shared__ char smem[109568];
  char* const tstp = smem;            // [64] rows x 1024 B, XOR-swizzled temporal
  char* const qdp  = smem + 65536;    // [64][136] f16 stride 272 (q dump) -- aliased:
  char* const scb  = smem + 65536;    //   [64][68] f32 stride 272 (scores)
  char* const vdp  = smem + 65536;    //   8 x [32][68] f16 stride 136 (vT dump)
  char* const kdp  = smem + 82944;    // [64][136] f16 stride 272 (k dump)
  char* const atn  = smem + 100352;   // [64][72] f16 stride 144 (attn probs)

  const int n    = blockIdx.x;
  const int tid  = threadIdx.x;
  const int wid  = tid >> 6;
  const int lane = tid & 63;
  const int quad = lane >> 4;
  const int l15  = lane & 15;
  const size_t scrbase = (size_t)n * 65536 + 32768;   // fp16 scratch (halfs)

  const _Float16* const Fq = WF;
  const _Float16* const Fk = WF + 262144;
  const _Float16* const Fv = WF + 524288;

  // ---- stage temporal ONCE: row = tid>>3 (64 rows), 8 threads/row ----
  {
    const int row = tid >> 3, si = tid & 7;
    const float* xr = x + ((size_t)row * NN + n) * DD;
    const float* pr = pos + (size_t)row * DD;
    char* const dst = tstp + row * 1024;
    const int swz = (row & 7) << 4;
    #pragma unroll
    for (int kb = 0; kb < 16; ++kb) {
      f32x4 xv = *(const f32x4*)(xr + kb * 32 + 4 * si);
      f32x4 pv = *(const f32x4*)(pr + kb * 32 + 4 * si);
      union { _Float16 h[4]; unsigned long long u; } o;
      #pragma unroll
      for (int j = 0; j < 4; ++j) o.h[j] = (_Float16)(xv[j] + pv[j]);
      *(unsigned long long*)(dst + ((kb * 64 + si * 8) ^ swz)) = o.u;
    }
  }
  __syncthreads();

  const int rswz = (l15 & 7) << 4;   // row&7 == l15&7 for rows 16*rt + l15
  f32x4 sacc[2] = {};   // this wave's 2 score tiles, accumulated over all 512 e

  for (int ph = 0; ph < 2; ++ph) {          // e in [ph*256, ph*256+256)
    f32x4 acc[4][4] = {};                   // q- or k-slice [64 t][64 e] of this wave
    const bool isK = (wid >= 4);
    const int  esl = wid & 3;
    const _Float16* const fwave =
        (isK ? Fk : Fq) + (size_t)(ph * 16 + esl * 4) * 8192 + (size_t)lane * 8;

    #pragma unroll
    for (int kb = 0; kb < 16; ++kb) {       // zero barriers: LDS tile is read-only
      f16x8 bf[4];                          // weight fragments straight from L2
      #pragma unroll
      for (int ct = 0; ct < 4; ++ct)
        bf[ct] = *(const f16x8*)(fwave + (size_t)kb * 512 + (size_t)ct * 8192);
      f16x8 af[4];
      #pragma unroll
      for (int rt = 0; rt < 4; ++rt)
        af[rt] = *(const f16x8*)(tstp + (16 * rt + l15) * 1024 +
                                 ((kb * 64 + quad * 16) ^ rswz));
      #pragma unroll
      for (int ct = 0; ct < 4; ++ct)
        #pragma unroll
        for (int rt = 0; rt < 4; ++rt)
          acc[rt][ct] = MFMA16(af[rt], bf[ct], acc[rt][ct]);
    }

    // dump 128-col blocks of q,k -> LDS, accumulate scores += q_c @ k_c^T
    for (int r = 0; r < 2; ++r) {
      __syncthreads();
      if ((esl >> 1) == r) {
        char* dst = isK ? kdp : qdp;
        const int colbase = (esl & 1) * 64;
        #pragma unroll
        for (int rt = 0; rt < 4; ++rt)
          #pragma unroll
          for (int ct = 0; ct < 4; ++ct)
            #pragma unroll
            for (int rg = 0; rg < 4; ++rg)
              *(_Float16*)(dst + (16*rt + quad*4 + rg)*272 + (colbase + 16*ct + l15)*2)
                  = (_Float16)acc[rt][ct][rg];
      }
      __syncthreads();
      const int srt = wid >> 1, sct0 = (wid & 1) * 2;
      #pragma unroll
      for (int ks = 0; ks < 4; ++ks) {
        f16x8 aq = *(const f16x8*)(qdp + (16*srt + l15)*272 + ks*64 + quad*16);
        #pragma unroll
        for (int j = 0; j < 2; ++j) {
          f16x8 bk = *(const f16x8*)(kdp + (16*(sct0+j) + l15)*272 + ks*64 + quad*16);
          sacc[j] = MFMA16(aq, bk, sacc[j]);
        }
      }
    }
  }

  // scores -> LDS (f32), causal softmax, attn probs (fp16) -> atn
  __syncthreads();
  {
    const int srt = wid >> 1, sct0 = (wid & 1) * 2;
    #pragma unroll
    for (int j = 0; j < 2; ++j)
      #pragma unroll
      for (int rg = 0; rg < 4; ++rg)
        *(float*)(scb + (16*srt + quad*4 + rg)*272 + (16*(sct0+j) + l15)*4) = sacc[j][rg];
  }
  __syncthreads();
  {
    const int row = tid >> 3, i = tid & 7;   // 8 threads per row, 8 cols each
    f32x4 s0 = *(const f32x4*)(scb + row*272 + 32*i);
    f32x4 s1 = *(const f32x4*)(scb + row*272 + 32*i + 16);
    float s[8] = { s0[0],s0[1],s0[2],s0[3], s1[0],s1[1],s1[2],s1[3] };
    float m = -3.0e38f;
    #pragma unroll
    for (int j = 0; j < 8; ++j) if (8*i + j <= row) m = fmaxf(m, s[j]);
    m = fmaxf(m, __shfl_xor(m, 1));
    m = fmaxf(m, __shfl_xor(m, 2));
    m = fmaxf(m, __shfl_xor(m, 4));
    float e[8]; float sum = 0.f;
    #pragma unroll
    for (int j = 0; j < 8; ++j) {
      e[j] = (8*i + j <= row) ? __expf(s[j] - m) : 0.f;   // NEG_BIG mask == exact zero
      sum += e[j];
    }
    sum += __shfl_xor(sum, 1);
    sum += __shfl_xor(sum, 2);
    sum += __shfl_xor(sum, 4);
    const float inv = 1.0f / sum;
    union { _Float16 h[8]; uint4 u; } o;
    #pragma unroll
    for (int j = 0; j < 8; ++j) o.h[j] = (_Float16)(e[j] * inv);
    *(uint4*)(atn + row*144 + 16*i) = o.u;
  }

  // V projection: wave w owns v[:, 64w..64w+63]; reads persistent tstp, no barriers.
  f32x4 vacc[4][4] = {};
  {
    const _Float16* const fwv = Fv + (size_t)(wid * 4) * 8192 + (size_t)lane * 8;
    #pragma unroll
    for (int kb = 0; kb < 16; ++kb) {
      f16x8 bf[4];
      #pragma unroll
      for (int ct = 0; ct < 4; ++ct)
        bf[ct] = *(const f16x8*)(fwv + (size_t)kb * 512 + (size_t)ct * 8192);
      f16x8 af[4];
      #pragma unroll
      for (int rt = 0; rt < 4; ++rt)
        af[rt] = *(const f16x8*)(tstp + (16 * rt + l15) * 1024 +
                                 ((kb * 64 + quad * 16) ^ rswz));
      #pragma unroll
      for (int ct = 0; ct < 4; ++ct)
        #pragma unroll
        for (int rt = 0; rt < 4; ++rt)
          vacc[rt][ct] = MFMA16(af[rt], bf[ct], vacc[rt][ct]);
    }
  }

  // out = attn @ v, computed transposed (D[m=d][n=t]) so stores pack 4 consecutive d.
  __syncthreads();   // softmax scb reads done before vdp overwrites the dump region
  char* const vd = vdp + wid * 4352;   // wave-private vT dump [32][68] f16 stride 136
  #pragma unroll
  for (int h = 0; h < 2; ++h) {
    #pragma unroll
    for (int c = 0; c < 2; ++c) {
      const int ct = 2*h + c;
      #pragma unroll
      for (int rt = 0; rt < 4; ++rt)
        #pragma unroll
        for (int rg = 0; rg < 4; ++rg)
          *(_Float16*)(vd + (16*c + l15)*136 + (16*rt + quad*4 + rg)*2)
              = (_Float16)vacc[rt][ct][rg];
    }
    f32x4 oacc[2][4] = {};
    #pragma unroll
    for (int ks = 0; ks < 2; ++ks) {
      f16x8 av[2];
      #pragma unroll
      for (int mt = 0; mt < 2; ++mt)
        av[mt] = *(const f16x8*)(vd + (16*mt + l15)*136 + ks*64 + quad*16);
      #pragma unroll
      for (int nt = 0; nt < 4; ++nt) {
        f16x8 ba = *(const f16x8*)(atn + (16*nt + l15)*144 + ks*64 + quad*16);
        #pragma unroll
        for (int mt = 0; mt < 2; ++mt)
          oacc[mt][nt] = MFMA16(av[mt], ba, oacc[mt][nt]);
      }
    }
    #pragma unroll
    for (int mt = 0; mt < 2; ++mt)
      #pragma unroll
      for (int nt = 0; nt < 4; ++nt) {
        const int d0 = 64*wid + 32*h + 16*mt + quad*4;
        const int tq = 16*nt + l15;
        union { _Float16 h4[4]; uint2 u; } o;
        #pragma unroll
        for (int rg = 0; rg < 4; ++rg) o.h4[rg] = (_Float16)oacc[mt][nt][rg];
        *(uint2*)(outp + scrbase + (size_t)tq * DD + d0) = o.u;   // fp16 scratch
      }
  }
}

// ---- ff = relu(out @ lin_w^T + b); y = 0.5*(ff+out) + (x+pos), fp32 output ----
// Scratch out-tile staged ONCE into 64KB swizzled LDS (2 blocks/CU); lin_w
// fragments direct from L2; zero in-loop barriers. Epilogue reads out-values
// from LDS, so in-place fp32 y writes never race the (dead) global scratch.
__global__ __launch_bounds__(512) void ff_final(
    const _Float16* __restrict__ outp, const float* __restrict__ x,
    const float* __restrict__ pos, const _Float16* __restrict__ lwF,
    const float* __restrict__ lb, float* __restrict__ y)
{
  __shared__ char smem[65536];   // out tile [64] rows x 1024 B, XOR-swizzled

  const int n = blockIdx.x;
  const int tid = threadIdx.x;
  const int wid = tid >> 6, lane = tid & 63, quad = lane >> 4, l15 = lane & 15;
  const size_t scrbase = (size_t)n * 65536 + 32768;

  // stage scratch -> LDS (fully coalesced: 64B contiguous per row-group)
  {
    const int row = tid >> 3, si = tid & 7;
    const _Float16* sr = outp + scrbase + (size_t)row * DD;
    char* const dst = smem + row * 1024;
    const int swz = (row & 7) << 4;
    #pragma unroll
    for (int kb = 0; kb < 16; ++kb)
      *(unsigned long long*)(dst + ((kb * 64 + si * 8) ^ swz)) =
          *(const unsigned long long*)(sr + kb * 32 + 4 * si);
  }
  __syncthreads();

  const int rswz = (l15 & 7) << 4;
  const _Float16* const fA = lwF + (size_t)(wid * 4) * 8192 + (size_t)lane * 8;

  f32x4 acc[4][4] = {};            // ffT [64 e of this wave][64 t]
  #pragma unroll
  for (int kb = 0; kb < 16; ++kb) {
    f16x8 af[4];                   // lin_w fragments straight from L2
    #pragma unroll
    for (int mt = 0; mt < 4; ++mt)
      af[mt] = *(const f16x8*)(fA + (size_t)kb * 512 + (size_t)mt * 8192);
    #pragma unroll
    for (int nt = 0; nt < 4; ++nt) {
      f16x8 bo = *(const f16x8*)(smem + (16 * nt + l15) * 1024 +
                                 ((kb * 64 + quad * 16) ^ rswz));
      #pragma unroll
      for (int mt = 0; mt < 4; ++mt)
        acc[mt][nt] = MFMA16(af[mt], bo, acc[mt][nt]);
    }
  }

  // epilogue: out-values from LDS; fp32 writes (clobber dead global scratch)
  #pragma unroll
  for (int mt = 0; mt < 4; ++mt) {
    const int e0 = wid*64 + 16*mt + quad*4;
    f32x4 bias = *(const f32x4*)(lb + e0);
    #pragma unroll
    for (int nt = 0; nt < 4; ++nt) {
      const int tq = 16*nt + l15;
      const size_t base = ((size_t)n * TT + tq) * DD + e0;
      union { _Float16 h4[4]; unsigned long long u; } ov;
      ov.u = *(const unsigned long long*)(smem + tq * 1024 + ((2 * e0) ^ rswz));
      f32x4 xv = *(const f32x4*)(x + ((size_t)tq * NN + n) * DD + e0);
      f32x4 pv = *(const f32x4*)(pos + (size_t)tq * DD + e0);
      f32x4 ro;
      #pragma unroll
      for (int rg = 0; rg < 4; ++rg) {
        float ff = acc[mt][nt][rg] + bias[rg];
        ff = ff > 0.f ? ff : 0.f;
        ro[rg] = 0.5f * (ff + (float)ov.h4[rg]) + xv[rg] + pv[rg];  // exact fp32 temporal
      }
      *(f32x4*)(y + base) = ro;
    }
  }
}

extern "C" void kernel_launch(void* const* d_in, const int* in_sizes, int n_in,
                              void* d_out, int out_size, void* d_ws, size_t ws_size,
                              hipStream_t stream) {
  (void)in_sizes; (void)n_in; (void)out_size; (void)ws_size;
  const float* x   = (const float*)d_in[0];
  const float* pos = (const float*)d_in[1];
  const float* Wq  = (const float*)d_in[2];
  const float* Wk  = (const float*)d_in[3];
  const float* Wv  = (const float*)d_in[4];
  const float* lw  = (const float*)d_in[5];
  const float* lb  = (const float*)d_in[6];
  _Float16* wsW = (_Float16*)d_ws;   // 4 * 262144 fp16 = 2 MB, fragment-major

  prep_weights<<<512, 256, 0, stream>>>(Wq, Wk, Wv, lw, wsW);
  attn_fused<<<2048, 512, 0, stream>>>(x, pos, wsW, (_Float16*)d_out);
  ff_final<<<2048, 512, 0, stream>>>((const _Float16*)d_out, x, pos,
                                     wsW + 786432, lb, (float*)d_out);
}